// Round 4
// baseline (1626.636 us; speedup 1.0000x reference)
//
#include <hip/hip_runtime.h>
#include <hip/hip_bf16.h>
#include <stdint.h>

#define Bv 128
#define Tv 512
#define Iv 64
#define Hv 512
#define Ov 64

typedef __attribute__((ext_vector_type(8))) short bv8;    // 8 bf16 for MFMA A/B
typedef __attribute__((ext_vector_type(4))) float fv4;    // MFMA C/D
typedef __attribute__((ext_vector_type(4))) unsigned uv4;
typedef __attribute__((ext_vector_type(2))) unsigned uv2;
typedef __attribute__((ext_vector_type(8))) unsigned short usv8;

static __device__ __forceinline__ unsigned short f2bf(float f) {
  unsigned u = __builtin_bit_cast(unsigned, f);
  u += 0x7fffu + ((u >> 16) & 1u);           // RNE
  return (unsigned short)(u >> 16);
}
static __device__ __forceinline__ float bf2f(unsigned short s) {
  return __builtin_bit_cast(float, ((unsigned)s) << 16);
}
static __device__ __forceinline__ float sgm(float a) {
  return __builtin_amdgcn_rcpf(1.0f + __expf(-a));
}

// DPP add: v += v_from_lane_pattern (patterns within 16-lane rows)
template <int CTRL>
static __device__ __forceinline__ float dpp_add(float v) {
  int t = __builtin_amdgcn_update_dpp(0, __builtin_bit_cast(int, v), CTRL, 0xF, 0xF, true);
  return v + __builtin_bit_cast(float, t);
}

// Full 64-lane sum, result replicated in every lane. VALU-latency only.
static __device__ __forceinline__ float wave_red(float v) {
  v = dpp_add<0xB1>(v);   // + v[lane^1]
  v = dpp_add<0x4E>(v);   // + v[lane^2]
  v = dpp_add<0x124>(v);  // row_ror:4
  v = dpp_add<0x128>(v);  // row_ror:8
  unsigned a = __builtin_bit_cast(unsigned, v);
  uv2 p = __builtin_amdgcn_permlane16_swap(a, a, false, false);
  v = __builtin_bit_cast(float, p[0]) + __builtin_bit_cast(float, p[1]);  // + v[lane^16]
  a = __builtin_bit_cast(unsigned, v);
  uv2 q = __builtin_amdgcn_permlane32_swap(a, a, false, false);
  v = __builtin_bit_cast(float, q[0]) + __builtin_bit_cast(float, q[1]);  // + v[lane^32]
  return v;
}

// ---------------------------------------------------------------------------
// K1: input projections. ir|iz packed bf16x2 -> traj region (u32/slot),
//     ih bf16 -> ws.  C = u[bt,64] @ W^T[64,512] via mfma_f32_16x16x32_bf16.
// ---------------------------------------------------------------------------
__global__ __launch_bounds__(256) void proj_kernel(
    const float* __restrict__ u,
    const float* __restrict__ Wir, const float* __restrict__ bir,
    const float* __restrict__ Wiz, const float* __restrict__ biz,
    const float* __restrict__ Wih, const float* __restrict__ bih,
    unsigned* __restrict__ irz, unsigned short* __restrict__ ihb)
{
  __shared__ __align__(16) unsigned short As[64][72];  // bf16, padded stride
  const int bt0 = blockIdx.x * 64;
  const int h0b = blockIdx.y * 64;
  const int tid = threadIdx.x;
  {  // stage u tile f32 -> bf16 LDS
    const int r = tid >> 2, ksg = (tid & 3) * 16;
    const float* src = u + (size_t)(bt0 + r) * Iv + ksg;
    unsigned short tmp[16];
#pragma unroll
    for (int i = 0; i < 16; i += 4) {
      float4 v = *(const float4*)(src + i);
      tmp[i] = f2bf(v.x); tmp[i+1] = f2bf(v.y); tmp[i+2] = f2bf(v.z); tmp[i+3] = f2bf(v.w);
    }
    *(uv4*)&As[r][ksg]     = *(uv4*)&tmp[0];
    *(uv4*)&As[r][ksg + 8] = *(uv4*)&tmp[8];
  }
  __syncthreads();
  const int wave = tid >> 6, lane = tid & 63;
  const int n = lane & 15, q = lane >> 4;
  const int h = h0b + wave * 16 + n;
  const float* Wg[3] = {Wir, Wiz, Wih};
  bv8 bfrag[3][2];
#pragma unroll
  for (int g = 0; g < 3; ++g)
#pragma unroll
    for (int ks = 0; ks < 2; ++ks) {
      const float* wp = Wg[g] + (size_t)h * Iv + ks * 32 + q * 8;
      float4 w0 = *(const float4*)wp, w1 = *(const float4*)(wp + 4);
      bv8 f;
      f[0] = (short)f2bf(w0.x); f[1] = (short)f2bf(w0.y);
      f[2] = (short)f2bf(w0.z); f[3] = (short)f2bf(w0.w);
      f[4] = (short)f2bf(w1.x); f[5] = (short)f2bf(w1.y);
      f[6] = (short)f2bf(w1.z); f[7] = (short)f2bf(w1.w);
      bfrag[g][ks] = f;
    }
  const float bs0 = bir[h], bs1 = biz[h], bs2 = bih[h];
#pragma unroll
  for (int sub = 0; sub < 4; ++sub) {
    bv8 a0 = *(const bv8*)&As[sub * 16 + n][q * 8];
    bv8 a1 = *(const bv8*)&As[sub * 16 + n][32 + q * 8];
    fv4 ar = {0.f,0.f,0.f,0.f}, az = {0.f,0.f,0.f,0.f}, ah = {0.f,0.f,0.f,0.f};
    ar = __builtin_amdgcn_mfma_f32_16x16x32_bf16(a0, bfrag[0][0], ar, 0, 0, 0);
    ar = __builtin_amdgcn_mfma_f32_16x16x32_bf16(a1, bfrag[0][1], ar, 0, 0, 0);
    az = __builtin_amdgcn_mfma_f32_16x16x32_bf16(a0, bfrag[1][0], az, 0, 0, 0);
    az = __builtin_amdgcn_mfma_f32_16x16x32_bf16(a1, bfrag[1][1], az, 0, 0, 0);
    ah = __builtin_amdgcn_mfma_f32_16x16x32_bf16(a0, bfrag[2][0], ah, 0, 0, 0);
    ah = __builtin_amdgcn_mfma_f32_16x16x32_bf16(a1, bfrag[2][1], ah, 0, 0, 0);
#pragma unroll
    for (int j = 0; j < 4; ++j) {
      const int row = bt0 + sub * 16 + q * 4 + j;   // C/D: col=lane&15, row=(lane>>4)*4+j
      const size_t slot = (size_t)row * Hv + h;
      irz[slot] = ((unsigned)f2bf(az[j] + bs1) << 16) | (unsigned)f2bf(ar[j] + bs0);
      ihb[slot] = f2bf(ah[j] + bs2);
    }
  }
}

// ---------------------------------------------------------------------------
// K2: the scan. 16 blocks x 8 waves (512 thr). Each wave owns ONE batch
// independently (b = blockIdx.x*8 + wave); lane owns h = lane*8..+7.
// NO inter-wave communication, NO barriers, NO LDS. The 8 waves land
// 2-per-SIMD: two independent batches interleave on each SIMD, so one
// wave's dependency-chain stalls are filled by the other's issue (TLP).
// Per-wave code identical to the R2 (676 us) version.
// ---------------------------------------------------------------------------
struct Buf { uv4 irz0, irz1; usv8 ih; fv4 nz0, nz1; };
#define IRZ(bf, j) ((j) < 4 ? (bf).irz0[(j)] : (bf).irz1[(j) - 4])
#define NZE(bf, j) ((j) < 4 ? (bf).nz0[(j)]  : (bf).nz1[(j) - 4])

__global__ __launch_bounds__(512, 2) void scan_kernel(
    const float* __restrict__ x0, const float* __restrict__ noise,
    const float* __restrict__ Nhr, const float* __restrict__ Mhr,
    const float* __restrict__ Nhz, const float* __restrict__ Mhz,
    const float* __restrict__ Nhh, const float* __restrict__ Mhh,
    unsigned* __restrict__ traj, const unsigned short* __restrict__ ihb,
    float* __restrict__ xlast)
{
  const int tid = threadIdx.x;
  const int wave = tid >> 6, lane = tid & 63;
  const int b = blockIdx.x * 8 + wave;
  const int h0 = lane * 8;
  fv4 nr[8], nz_[8], nh[8], mr[8], mz[8], mh[8];
#pragma unroll
  for (int j = 0; j < 8; ++j) {
    nr[j]  = *(const fv4*)(Nhr + (size_t)(h0 + j) * 4);
    nz_[j] = *(const fv4*)(Nhz + (size_t)(h0 + j) * 4);
    nh[j]  = *(const fv4*)(Nhh + (size_t)(h0 + j) * 4);
    mr[j]  = *(const fv4*)(Mhr + (size_t)(h0 + j) * 4);
    mz[j]  = *(const fv4*)(Mhz + (size_t)(h0 + j) * 4);
    mh[j]  = *(const fv4*)(Mhh + (size_t)(h0 + j) * 4);
  }
  // Pin matrix fragments (same as R2): opaque to the compiler so it cannot
  // re-load them from global inside the t-loop.
#pragma unroll
  for (int j = 0; j < 8; ++j) {
    asm("" : "+v"(nr[j]), "+v"(nz_[j]), "+v"(nh[j]));
    asm("" : "+v"(mr[j]), "+v"(mz[j]), "+v"(mh[j]));
  }
  float x[8];
  {
    fv4 a = *(const fv4*)(x0 + (size_t)b * Hv + h0);
    fv4 c = *(const fv4*)(x0 + (size_t)b * Hv + h0 + 4);
#pragma unroll
    for (int j = 0; j < 4; ++j) { x[j] = a[j]; x[j + 4] = c[j]; }
  }
  const size_t rowbase = (size_t)b * Tv * Hv + h0;
  const size_t nbase = (size_t)b * Hv + h0;
  Buf A, Bb;
  auto LOAD = [&](Buf& bf, int t) {
    const unsigned* p = traj + rowbase + (size_t)t * Hv;
    bf.irz0 = *(const uv4*)p;
    bf.irz1 = *(const uv4*)(p + 4);
    bf.ih = *(const usv8*)(ihb + rowbase + (size_t)t * Hv);
    const float* np = noise + (size_t)t * (Bv * Hv) + nbase;
    bf.nz0 = *(const fv4*)np;
    bf.nz1 = *(const fv4*)(np + 4);
  };
  const float sc = 1.0f / 512.0f;
  auto STEP = [&](const Buf& bf, int t) {
    float sr[4] = {0, 0, 0, 0}, sz[4] = {0, 0, 0, 0};
#pragma unroll
    for (int j = 0; j < 8; ++j)
#pragma unroll
      for (int r = 0; r < 4; ++r) {
        sr[r] = fmaf(x[j], nr[j][r], sr[r]);
        sz[r] = fmaf(x[j], nz_[j][r], sz[r]);
      }
#pragma unroll
    for (int r = 0; r < 4; ++r) {
      sr[r] = wave_red(sr[r]) * sc;
      sz[r] = wave_red(sz[r]) * sc;
    }
    float rr[8], zz[8];
#pragma unroll
    for (int j = 0; j < 8; ++j) {
      float hr = fmaf(sr[3], mr[j][3], fmaf(sr[2], mr[j][2], fmaf(sr[1], mr[j][1], sr[0] * mr[j][0])));
      float hz = fmaf(sz[3], mz[j][3], fmaf(sz[2], mz[j][2], fmaf(sz[1], mz[j][1], sz[0] * mz[j][0])));
      unsigned w = IRZ(bf, j);
      rr[j] = sgm(bf2f((unsigned short)(w & 0xffffu)) + hr);
      zz[j] = sgm(bf2f((unsigned short)(w >> 16)) + hz);
    }
    float sh[4] = {0, 0, 0, 0};
#pragma unroll
    for (int j = 0; j < 8; ++j) {
      float rx = rr[j] * x[j];
#pragma unroll
      for (int r = 0; r < 4; ++r) sh[r] = fmaf(rx, nh[j][r], sh[r]);
    }
#pragma unroll
    for (int r = 0; r < 4; ++r) sh[r] = wave_red(sh[r]) * sc;
#pragma unroll
    for (int j = 0; j < 8; ++j) {
      float hh = fmaf(sh[3], mh[j][3], fmaf(sh[2], mh[j][2], fmaf(sh[1], mh[j][1], sh[0] * mh[j][0])));
      float a = bf2f(bf.ih[j]) + hh;
      a = fminf(fmaxf(a, -15.f), 15.f);
      float e = __expf(-2.f * a);
      float g = (1.f - e) * __builtin_amdgcn_rcpf(1.f + e);  // tanh
      x[j] = x[j] + 0.05f * NZE(bf, j) + 0.2f * (1.f - zz[j]) * (g - x[j]);
    }
    float* op = (float*)(traj + rowbase + (size_t)t * Hv);
    fv4 s0 = {x[0], x[1], x[2], x[3]}, s1 = {x[4], x[5], x[6], x[7]};
    *(fv4*)op = s0;
    *(fv4*)(op + 4) = s1;
  };
  LOAD(A, 0);
  for (int t = 0; t < Tv; t += 2) {
    LOAD(Bb, t + 1);
    STEP(A, t);
    if (t + 2 < Tv) LOAD(A, t + 2);
    STEP(Bb, t + 1);
  }
  {
    fv4 s0 = {x[0], x[1], x[2], x[3]}, s1 = {x[4], x[5], x[6], x[7]};
    *(fv4*)(xlast + nbase) = s0;
    *(fv4*)(xlast + nbase + 4) = s1;
  }
}

// ---------------------------------------------------------------------------
// K3: output projection out[bt,o] = traj[bt,:] . W_out[o,:] + b_out[o]
// ---------------------------------------------------------------------------
__global__ __launch_bounds__(256) void outproj_kernel(
    const float* __restrict__ traj, const float* __restrict__ Wout,
    const float* __restrict__ bout, float* __restrict__ out)
{
  __shared__ __align__(16) unsigned short As[64][40];
  const int bt0 = blockIdx.x * 64;
  const int tid = threadIdx.x;
  const int wave = tid >> 6, lane = tid & 63;
  const int n = lane & 15, q = lane >> 4;
  const int o = wave * 16 + n;
  const float bo = bout[o];
  fv4 acc[4] = {{0.f,0.f,0.f,0.f},{0.f,0.f,0.f,0.f},{0.f,0.f,0.f,0.f},{0.f,0.f,0.f,0.f}};
  const int r = tid >> 2, ksg = (tid & 3) * 8;
  for (int ks = 0; ks < 16; ++ks) {
    __syncthreads();
    {
      const float* src = traj + (size_t)(bt0 + r) * Hv + ks * 32 + ksg;
      float4 v0 = *(const float4*)src, v1 = *(const float4*)(src + 4);
      unsigned short tmp[8];
      tmp[0] = f2bf(v0.x); tmp[1] = f2bf(v0.y); tmp[2] = f2bf(v0.z); tmp[3] = f2bf(v0.w);
      tmp[4] = f2bf(v1.x); tmp[5] = f2bf(v1.y); tmp[6] = f2bf(v1.z); tmp[7] = f2bf(v1.w);
      *(uv4*)&As[r][ksg] = *(uv4*)&tmp[0];
    }
    __syncthreads();
    const float* wp = Wout + (size_t)o * Hv + ks * 32 + q * 8;
    float4 w0 = *(const float4*)wp, w1 = *(const float4*)(wp + 4);
    bv8 bf;
    bf[0] = (short)f2bf(w0.x); bf[1] = (short)f2bf(w0.y);
    bf[2] = (short)f2bf(w0.z); bf[3] = (short)f2bf(w0.w);
    bf[4] = (short)f2bf(w1.x); bf[5] = (short)f2bf(w1.y);
    bf[6] = (short)f2bf(w1.z); bf[7] = (short)f2bf(w1.w);
#pragma unroll
    for (int sub = 0; sub < 4; ++sub) {
      bv8 af = *(const bv8*)&As[sub * 16 + n][q * 8];
      acc[sub] = __builtin_amdgcn_mfma_f32_16x16x32_bf16(af, bf, acc[sub], 0, 0, 0);
    }
  }
#pragma unroll
  for (int sub = 0; sub < 4; ++sub)
#pragma unroll
    for (int j = 0; j < 4; ++j) {
      const int row = bt0 + sub * 16 + q * 4 + j;
      out[(size_t)row * Ov + o] = acc[sub][j] + bo;
    }
}

// ---------------------------------------------------------------------------
extern "C" void kernel_launch(void* const* d_in, const int* in_sizes, int n_in,
                              void* d_out, int out_size, void* d_ws, size_t ws_size,
                              hipStream_t stream) {
  const float* u    = (const float*)d_in[0];
  const float* x0   = (const float*)d_in[1];
  const float* noise= (const float*)d_in[2];
  const float* Wir  = (const float*)d_in[3];
  const float* bir  = (const float*)d_in[4];
  const float* Wiz  = (const float*)d_in[5];
  const float* biz  = (const float*)d_in[6];
  const float* Wih  = (const float*)d_in[7];
  const float* bih  = (const float*)d_in[8];
  const float* Nhr  = (const float*)d_in[9];
  const float* Mhr  = (const float*)d_in[10];
  const float* Nhz  = (const float*)d_in[11];
  const float* Mhz  = (const float*)d_in[12];
  const float* Nhh  = (const float*)d_in[13];
  const float* Mhh  = (const float*)d_in[14];
  const float* Wout = (const float*)d_in[15];
  const float* bout = (const float*)d_in[16];

  float* out   = (float*)d_out;                    // [B,T,O]
  float* xlast = out + (size_t)Bv * Tv * Ov;       // [B,H]
  float* traj  = xlast + (size_t)Bv * Hv;          // [B,T,H]
  unsigned short* ihbuf = (unsigned short*)d_ws;   // [B*T*H] bf16 (64 MiB)

  proj_kernel<<<dim3(1024, 8, 1), 256, 0, stream>>>(
      u, Wir, bir, Wiz, biz, Wih, bih, (unsigned*)traj, ihbuf);
  scan_kernel<<<dim3(16, 1, 1), 512, 0, stream>>>(
      x0, noise, Nhr, Mhr, Nhz, Mhz, Nhh, Mhh, (unsigned*)traj, ihbuf, xlast);
  outproj_kernel<<<dim3(1024, 1, 1), 256, 0, stream>>>(traj, Wout, bout, out);
}

// Round 5
// 1520.356 us; speedup vs baseline: 1.0699x; 1.0699x over previous
//
#include <hip/hip_runtime.h>
#include <hip/hip_bf16.h>
#include <stdint.h>

#define Bv 128
#define Tv 512
#define Iv 64
#define Hv 512
#define Ov 64

typedef __attribute__((ext_vector_type(8))) short bv8;    // 8 bf16 for MFMA A/B
typedef __attribute__((ext_vector_type(4))) float fv4;    // MFMA C/D
typedef __attribute__((ext_vector_type(4))) unsigned uv4;
typedef __attribute__((ext_vector_type(2))) unsigned uv2;
typedef __attribute__((ext_vector_type(8))) unsigned short usv8;

static __device__ __forceinline__ unsigned short f2bf(float f) {
  unsigned u = __builtin_bit_cast(unsigned, f);
  u += 0x7fffu + ((u >> 16) & 1u);           // RNE
  return (unsigned short)(u >> 16);
}
static __device__ __forceinline__ float bf2f(unsigned short s) {
  return __builtin_bit_cast(float, ((unsigned)s) << 16);
}
static __device__ __forceinline__ float sgm(float a) {
  return __builtin_amdgcn_rcpf(1.0f + __expf(-a));
}

// DPP add: v += v_from_lane_pattern (patterns within 16-lane rows)
template <int CTRL>
static __device__ __forceinline__ float dpp_add(float v) {
  int t = __builtin_amdgcn_update_dpp(0, __builtin_bit_cast(int, v), CTRL, 0xF, 0xF, true);
  return v + __builtin_bit_cast(float, t);
}

// Full 64-lane sum, result replicated in every lane. VALU-latency only.
static __device__ __forceinline__ float wave_red(float v) {
  v = dpp_add<0xB1>(v);   // + v[lane^1]
  v = dpp_add<0x4E>(v);   // + v[lane^2]
  v = dpp_add<0x124>(v);  // row_ror:4
  v = dpp_add<0x128>(v);  // row_ror:8
  unsigned a = __builtin_bit_cast(unsigned, v);
  uv2 p = __builtin_amdgcn_permlane16_swap(a, a, false, false);
  v = __builtin_bit_cast(float, p[0]) + __builtin_bit_cast(float, p[1]);  // + v[lane^16]
  a = __builtin_bit_cast(unsigned, v);
  uv2 q = __builtin_amdgcn_permlane32_swap(a, a, false, false);
  v = __builtin_bit_cast(float, q[0]) + __builtin_bit_cast(float, q[1]);  // + v[lane^32]
  return v;
}

// ---------------------------------------------------------------------------
// K1: input projections. ir|iz packed bf16x2 -> traj region (u32/slot),
//     ih bf16 -> ws.  C = u[bt,64] @ W^T[64,512] via mfma_f32_16x16x32_bf16.
// ---------------------------------------------------------------------------
__global__ __launch_bounds__(256) void proj_kernel(
    const float* __restrict__ u,
    const float* __restrict__ Wir, const float* __restrict__ bir,
    const float* __restrict__ Wiz, const float* __restrict__ biz,
    const float* __restrict__ Wih, const float* __restrict__ bih,
    unsigned* __restrict__ irz, unsigned short* __restrict__ ihb)
{
  __shared__ __align__(16) unsigned short As[64][72];  // bf16, padded stride
  const int bt0 = blockIdx.x * 64;
  const int h0b = blockIdx.y * 64;
  const int tid = threadIdx.x;
  {  // stage u tile f32 -> bf16 LDS
    const int r = tid >> 2, ksg = (tid & 3) * 16;
    const float* src = u + (size_t)(bt0 + r) * Iv + ksg;
    unsigned short tmp[16];
#pragma unroll
    for (int i = 0; i < 16; i += 4) {
      float4 v = *(const float4*)(src + i);
      tmp[i] = f2bf(v.x); tmp[i+1] = f2bf(v.y); tmp[i+2] = f2bf(v.z); tmp[i+3] = f2bf(v.w);
    }
    *(uv4*)&As[r][ksg]     = *(uv4*)&tmp[0];
    *(uv4*)&As[r][ksg + 8] = *(uv4*)&tmp[8];
  }
  __syncthreads();
  const int wave = tid >> 6, lane = tid & 63;
  const int n = lane & 15, q = lane >> 4;
  const int h = h0b + wave * 16 + n;
  const float* Wg[3] = {Wir, Wiz, Wih};
  bv8 bfrag[3][2];
#pragma unroll
  for (int g = 0; g < 3; ++g)
#pragma unroll
    for (int ks = 0; ks < 2; ++ks) {
      const float* wp = Wg[g] + (size_t)h * Iv + ks * 32 + q * 8;
      float4 w0 = *(const float4*)wp, w1 = *(const float4*)(wp + 4);
      bv8 f;
      f[0] = (short)f2bf(w0.x); f[1] = (short)f2bf(w0.y);
      f[2] = (short)f2bf(w0.z); f[3] = (short)f2bf(w0.w);
      f[4] = (short)f2bf(w1.x); f[5] = (short)f2bf(w1.y);
      f[6] = (short)f2bf(w1.z); f[7] = (short)f2bf(w1.w);
      bfrag[g][ks] = f;
    }
  const float bs0 = bir[h], bs1 = biz[h], bs2 = bih[h];
#pragma unroll
  for (int sub = 0; sub < 4; ++sub) {
    bv8 a0 = *(const bv8*)&As[sub * 16 + n][q * 8];
    bv8 a1 = *(const bv8*)&As[sub * 16 + n][32 + q * 8];
    fv4 ar = {0.f,0.f,0.f,0.f}, az = {0.f,0.f,0.f,0.f}, ah = {0.f,0.f,0.f,0.f};
    ar = __builtin_amdgcn_mfma_f32_16x16x32_bf16(a0, bfrag[0][0], ar, 0, 0, 0);
    ar = __builtin_amdgcn_mfma_f32_16x16x32_bf16(a1, bfrag[0][1], ar, 0, 0, 0);
    az = __builtin_amdgcn_mfma_f32_16x16x32_bf16(a0, bfrag[1][0], az, 0, 0, 0);
    az = __builtin_amdgcn_mfma_f32_16x16x32_bf16(a1, bfrag[1][1], az, 0, 0, 0);
    ah = __builtin_amdgcn_mfma_f32_16x16x32_bf16(a0, bfrag[2][0], ah, 0, 0, 0);
    ah = __builtin_amdgcn_mfma_f32_16x16x32_bf16(a1, bfrag[2][1], ah, 0, 0, 0);
#pragma unroll
    for (int j = 0; j < 4; ++j) {
      const int row = bt0 + sub * 16 + q * 4 + j;   // C/D: col=lane&15, row=(lane>>4)*4+j
      const size_t slot = (size_t)row * Hv + h;
      irz[slot] = ((unsigned)f2bf(az[j] + bs1) << 16) | (unsigned)f2bf(ar[j] + bs0);
      ihb[slot] = f2bf(ah[j] + bs2);
    }
  }
}

// ---------------------------------------------------------------------------
// K2: the scan. 64 blocks x 1 wave; each wave owns TWO batches (ILP):
// the two batches' dependency chains are independent and interleaved
// phase-by-phase, so one chain's latency hides under the other's issue.
// Weight matrices are SHARED between the two batches (192 floats once).
// Lane owns h = lane*8..+7 for both batches. No barriers, no LDS.
// ---------------------------------------------------------------------------
struct Buf { uv4 irz0, irz1; usv8 ih; fv4 nz0, nz1; };
#define IRZ(bf, j) ((j) < 4 ? (bf).irz0[(j)] : (bf).irz1[(j) - 4])
#define NZE(bf, j) ((j) < 4 ? (bf).nz0[(j)]  : (bf).nz1[(j) - 4])

__global__ __launch_bounds__(64, 1) void scan_kernel(
    const float* __restrict__ x0, const float* __restrict__ noise,
    const float* __restrict__ Nhr, const float* __restrict__ Mhr,
    const float* __restrict__ Nhz, const float* __restrict__ Mhz,
    const float* __restrict__ Nhh, const float* __restrict__ Mhh,
    unsigned* __restrict__ traj, const unsigned short* __restrict__ ihb,
    float* __restrict__ xlast)
{
  const int lane = threadIdx.x;
  const int h0 = lane * 8;
  fv4 nr[8], nz_[8], nh[8], mr[8], mz[8], mh[8];
#pragma unroll
  for (int j = 0; j < 8; ++j) {
    nr[j]  = *(const fv4*)(Nhr + (size_t)(h0 + j) * 4);
    nz_[j] = *(const fv4*)(Nhz + (size_t)(h0 + j) * 4);
    nh[j]  = *(const fv4*)(Nhh + (size_t)(h0 + j) * 4);
    mr[j]  = *(const fv4*)(Mhr + (size_t)(h0 + j) * 4);
    mz[j]  = *(const fv4*)(Mhz + (size_t)(h0 + j) * 4);
    mh[j]  = *(const fv4*)(Mhh + (size_t)(h0 + j) * 4);
  }
#pragma unroll
  for (int j = 0; j < 8; ++j) {
    asm("" : "+v"(nr[j]), "+v"(nz_[j]), "+v"(nh[j]));
    asm("" : "+v"(mr[j]), "+v"(mz[j]), "+v"(mh[j]));
  }
  float x[2][8];
  size_t rowbase[2], nbase[2];
#pragma unroll
  for (int g = 0; g < 2; ++g) {
    const int b = blockIdx.x * 2 + g;
    fv4 a = *(const fv4*)(x0 + (size_t)b * Hv + h0);
    fv4 c = *(const fv4*)(x0 + (size_t)b * Hv + h0 + 4);
#pragma unroll
    for (int j = 0; j < 4; ++j) { x[g][j] = a[j]; x[g][j + 4] = c[j]; }
    rowbase[g] = (size_t)b * Tv * Hv + h0;
    nbase[g]   = (size_t)b * Hv + h0;
  }
  Buf PA[2], PB[2];
  auto LOAD = [&](Buf (&bf)[2], int t) {
#pragma unroll
    for (int g = 0; g < 2; ++g) {
      const unsigned* p = traj + rowbase[g] + (size_t)t * Hv;
      bf[g].irz0 = *(const uv4*)p;
      bf[g].irz1 = *(const uv4*)(p + 4);
      bf[g].ih   = *(const usv8*)(ihb + rowbase[g] + (size_t)t * Hv);
      const float* np = noise + (size_t)t * (Bv * Hv) + nbase[g];
      bf[g].nz0 = *(const fv4*)np;
      bf[g].nz1 = *(const fv4*)(np + 4);
    }
  };
  const float sc = 1.0f / 512.0f;
  auto STEP = [&](const Buf (&bf)[2], int t) {
    // phase 1: low-rank N projections for r,z — both batches interleaved
    float sr[2][4] = {{0,0,0,0},{0,0,0,0}}, sz[2][4] = {{0,0,0,0},{0,0,0,0}};
#pragma unroll
    for (int j = 0; j < 8; ++j)
#pragma unroll
      for (int g = 0; g < 2; ++g)
#pragma unroll
        for (int r = 0; r < 4; ++r) {
          sr[g][r] = fmaf(x[g][j], nr[j][r], sr[g][r]);
          sz[g][r] = fmaf(x[g][j], nz_[j][r], sz[g][r]);
        }
    // phase 2: 16 independent wave reductions
#pragma unroll
    for (int g = 0; g < 2; ++g)
#pragma unroll
      for (int r = 0; r < 4; ++r) {
        sr[g][r] = wave_red(sr[g][r]) * sc;
        sz[g][r] = wave_red(sz[g][r]) * sc;
      }
    // phase 3: gates r,z ; keep rx (=r*x) and zz
    float rx[2][8], zz[2][8];
#pragma unroll
    for (int j = 0; j < 8; ++j)
#pragma unroll
      for (int g = 0; g < 2; ++g) {
        float hr = fmaf(sr[g][3], mr[j][3], fmaf(sr[g][2], mr[j][2], fmaf(sr[g][1], mr[j][1], sr[g][0] * mr[j][0])));
        float hz = fmaf(sz[g][3], mz[j][3], fmaf(sz[g][2], mz[j][2], fmaf(sz[g][1], mz[j][1], sz[g][0] * mz[j][0])));
        unsigned w = IRZ(bf[g], j);
        rx[g][j] = sgm(bf2f((unsigned short)(w & 0xffffu)) + hr) * x[g][j];
        zz[g][j] = sgm(bf2f((unsigned short)(w >> 16)) + hz);
      }
    // phase 4: N projection of r*x
    float sh[2][4] = {{0,0,0,0},{0,0,0,0}};
#pragma unroll
    for (int j = 0; j < 8; ++j)
#pragma unroll
      for (int g = 0; g < 2; ++g)
#pragma unroll
        for (int r = 0; r < 4; ++r) sh[g][r] = fmaf(rx[g][j], nh[j][r], sh[g][r]);
    // phase 5: 8 reductions
#pragma unroll
    for (int g = 0; g < 2; ++g)
#pragma unroll
      for (int r = 0; r < 4; ++r) sh[g][r] = wave_red(sh[g][r]) * sc;
    // phase 6: tanh gate + state update + store
#pragma unroll
    for (int j = 0; j < 8; ++j)
#pragma unroll
      for (int g = 0; g < 2; ++g) {
        float hh = fmaf(sh[g][3], mh[j][3], fmaf(sh[g][2], mh[j][2], fmaf(sh[g][1], mh[j][1], sh[g][0] * mh[j][0])));
        float a = fmaxf(bf2f(bf[g].ih[j]) + hh, -15.f);   // one-sided clamp: a>=-15 keeps exp finite
        float e = __expf(-2.f * a);
        float g_ = (1.f - e) * __builtin_amdgcn_rcpf(1.f + e);  // tanh
        x[g][j] = x[g][j] + 0.05f * NZE(bf[g], j) + 0.2f * (1.f - zz[g][j]) * (g_ - x[g][j]);
      }
#pragma unroll
    for (int g = 0; g < 2; ++g) {
      float* op = (float*)(traj + rowbase[g] + (size_t)t * Hv);
      fv4 s0 = {x[g][0], x[g][1], x[g][2], x[g][3]};
      fv4 s1 = {x[g][4], x[g][5], x[g][6], x[g][7]};
      *(fv4*)op = s0;
      *(fv4*)(op + 4) = s1;
    }
  };
  LOAD(PA, 0);
  for (int t = 0; t < Tv; t += 2) {
    LOAD(PB, t + 1);
    STEP(PA, t);
    if (t + 2 < Tv) LOAD(PA, t + 2);
    STEP(PB, t + 1);
  }
#pragma unroll
  for (int g = 0; g < 2; ++g) {
    fv4 s0 = {x[g][0], x[g][1], x[g][2], x[g][3]};
    fv4 s1 = {x[g][4], x[g][5], x[g][6], x[g][7]};
    *(fv4*)(xlast + nbase[g]) = s0;
    *(fv4*)(xlast + nbase[g] + 4) = s1;
  }
}

// ---------------------------------------------------------------------------
// K3: output projection out[bt,o] = traj[bt,:] . W_out[o,:] + b_out[o]
// ---------------------------------------------------------------------------
__global__ __launch_bounds__(256) void outproj_kernel(
    const float* __restrict__ traj, const float* __restrict__ Wout,
    const float* __restrict__ bout, float* __restrict__ out)
{
  __shared__ __align__(16) unsigned short As[64][40];
  const int bt0 = blockIdx.x * 64;
  const int tid = threadIdx.x;
  const int wave = tid >> 6, lane = tid & 63;
  const int n = lane & 15, q = lane >> 4;
  const int o = wave * 16 + n;
  const float bo = bout[o];
  fv4 acc[4] = {{0.f,0.f,0.f,0.f},{0.f,0.f,0.f,0.f},{0.f,0.f,0.f,0.f},{0.f,0.f,0.f,0.f}};
  const int r = tid >> 2, ksg = (tid & 3) * 8;
  for (int ks = 0; ks < 16; ++ks) {
    __syncthreads();
    {
      const float* src = traj + (size_t)(bt0 + r) * Hv + ks * 32 + ksg;
      float4 v0 = *(const float4*)src, v1 = *(const float4*)(src + 4);
      unsigned short tmp[8];
      tmp[0] = f2bf(v0.x); tmp[1] = f2bf(v0.y); tmp[2] = f2bf(v0.z); tmp[3] = f2bf(v0.w);
      tmp[4] = f2bf(v1.x); tmp[5] = f2bf(v1.y); tmp[6] = f2bf(v1.z); tmp[7] = f2bf(v1.w);
      *(uv4*)&As[r][ksg] = *(uv4*)&tmp[0];
    }
    __syncthreads();
    const float* wp = Wout + (size_t)o * Hv + ks * 32 + q * 8;
    float4 w0 = *(const float4*)wp, w1 = *(const float4*)(wp + 4);
    bv8 bf;
    bf[0] = (short)f2bf(w0.x); bf[1] = (short)f2bf(w0.y);
    bf[2] = (short)f2bf(w0.z); bf[3] = (short)f2bf(w0.w);
    bf[4] = (short)f2bf(w1.x); bf[5] = (short)f2bf(w1.y);
    bf[6] = (short)f2bf(w1.z); bf[7] = (short)f2bf(w1.w);
#pragma unroll
    for (int sub = 0; sub < 4; ++sub) {
      bv8 af = *(const bv8*)&As[sub * 16 + n][q * 8];
      acc[sub] = __builtin_amdgcn_mfma_f32_16x16x32_bf16(af, bf, acc[sub], 0, 0, 0);
    }
  }
#pragma unroll
  for (int sub = 0; sub < 4; ++sub)
#pragma unroll
    for (int j = 0; j < 4; ++j) {
      const int row = bt0 + sub * 16 + q * 4 + j;
      out[(size_t)row * Ov + o] = acc[sub][j] + bo;
    }
}

// ---------------------------------------------------------------------------
extern "C" void kernel_launch(void* const* d_in, const int* in_sizes, int n_in,
                              void* d_out, int out_size, void* d_ws, size_t ws_size,
                              hipStream_t stream) {
  const float* u    = (const float*)d_in[0];
  const float* x0   = (const float*)d_in[1];
  const float* noise= (const float*)d_in[2];
  const float* Wir  = (const float*)d_in[3];
  const float* bir  = (const float*)d_in[4];
  const float* Wiz  = (const float*)d_in[5];
  const float* biz  = (const float*)d_in[6];
  const float* Wih  = (const float*)d_in[7];
  const float* bih  = (const float*)d_in[8];
  const float* Nhr  = (const float*)d_in[9];
  const float* Mhr  = (const float*)d_in[10];
  const float* Nhz  = (const float*)d_in[11];
  const float* Mhz  = (const float*)d_in[12];
  const float* Nhh  = (const float*)d_in[13];
  const float* Mhh  = (const float*)d_in[14];
  const float* Wout = (const float*)d_in[15];
  const float* bout = (const float*)d_in[16];

  float* out   = (float*)d_out;                    // [B,T,O]
  float* xlast = out + (size_t)Bv * Tv * Ov;       // [B,H]
  float* traj  = xlast + (size_t)Bv * Hv;          // [B,T,H]
  unsigned short* ihbuf = (unsigned short*)d_ws;   // [B*T*H] bf16 (64 MiB)

  proj_kernel<<<dim3(1024, 8, 1), 256, 0, stream>>>(
      u, Wir, bir, Wiz, biz, Wih, bih, (unsigned*)traj, ihbuf);
  scan_kernel<<<dim3(64, 1, 1), 64, 0, stream>>>(
      x0, noise, Nhr, Mhr, Nhz, Mhz, Nhh, Mhh, (unsigned*)traj, ihbuf, xlast);
  outproj_kernel<<<dim3(1024, 1, 1), 256, 0, stream>>>(traj, Wout, bout, out);
}

// Round 6
// 724.645 us; speedup vs baseline: 2.2447x; 2.0981x over previous
//
#include <hip/hip_runtime.h>
#include <hip/hip_bf16.h>
#include <stdint.h>

#define Bv 128
#define Tv 512
#define Iv 64
#define Hv 512
#define Ov 64

typedef __attribute__((ext_vector_type(8))) short bv8;    // 8 bf16 for MFMA A/B
typedef __attribute__((ext_vector_type(4))) float fv4;    // MFMA C/D
typedef __attribute__((ext_vector_type(4))) unsigned uv4;
typedef __attribute__((ext_vector_type(2))) unsigned uv2;
typedef __attribute__((ext_vector_type(8))) unsigned short usv8;

#define LOG2E 1.44269504f
#define TWOLOG2E 2.88539008f

static __device__ __forceinline__ unsigned short f2bf(float f) {
  unsigned u = __builtin_bit_cast(unsigned, f);
  u += 0x7fffu + ((u >> 16) & 1u);           // RNE
  return (unsigned short)(u >> 16);
}
static __device__ __forceinline__ float bf2f(unsigned short s) {
  return __builtin_bit_cast(float, ((unsigned)s) << 16);
}

// DPP add: v += v_from_lane_pattern (patterns within 16-lane rows)
template <int CTRL>
static __device__ __forceinline__ float dpp_add(float v) {
  int t = __builtin_amdgcn_update_dpp(0, __builtin_bit_cast(int, v), CTRL, 0xF, 0xF, true);
  return v + __builtin_bit_cast(float, t);
}

// Full 64-lane sum, result replicated in every lane. VALU-latency only.
static __device__ __forceinline__ float wave_red(float v) {
  v = dpp_add<0xB1>(v);   // + v[lane^1]
  v = dpp_add<0x4E>(v);   // + v[lane^2]
  v = dpp_add<0x124>(v);  // row_ror:4
  v = dpp_add<0x128>(v);  // row_ror:8
  unsigned a = __builtin_bit_cast(unsigned, v);
  uv2 p = __builtin_amdgcn_permlane16_swap(a, a, false, false);
  v = __builtin_bit_cast(float, p[0]) + __builtin_bit_cast(float, p[1]);  // + v[lane^16]
  a = __builtin_bit_cast(unsigned, v);
  uv2 q = __builtin_amdgcn_permlane32_swap(a, a, false, false);
  v = __builtin_bit_cast(float, q[0]) + __builtin_bit_cast(float, q[1]);  // + v[lane^32]
  return v;
}

// ---------------------------------------------------------------------------
// K1: input projections. ir|iz packed bf16x2 -> traj region (u32/slot),
//     ih bf16 -> ws.  C = u[bt,64] @ W^T[64,512] via mfma_f32_16x16x32_bf16.
// log2e folded into W_ir/b_ir and W_iz/b_iz; 2*log2e into W_ih/b_ih, so the
// scan kernel can use raw v_exp_f32 (exp2) with no argument scaling.
// ---------------------------------------------------------------------------
__global__ __launch_bounds__(256) void proj_kernel(
    const float* __restrict__ u,
    const float* __restrict__ Wir, const float* __restrict__ bir,
    const float* __restrict__ Wiz, const float* __restrict__ biz,
    const float* __restrict__ Wih, const float* __restrict__ bih,
    unsigned* __restrict__ irz, unsigned short* __restrict__ ihb)
{
  __shared__ __align__(16) unsigned short As[64][72];  // bf16, padded stride
  const int bt0 = blockIdx.x * 64;
  const int h0b = blockIdx.y * 64;
  const int tid = threadIdx.x;
  {  // stage u tile f32 -> bf16 LDS
    const int r = tid >> 2, ksg = (tid & 3) * 16;
    const float* src = u + (size_t)(bt0 + r) * Iv + ksg;
    unsigned short tmp[16];
#pragma unroll
    for (int i = 0; i < 16; i += 4) {
      float4 v = *(const float4*)(src + i);
      tmp[i] = f2bf(v.x); tmp[i+1] = f2bf(v.y); tmp[i+2] = f2bf(v.z); tmp[i+3] = f2bf(v.w);
    }
    *(uv4*)&As[r][ksg]     = *(uv4*)&tmp[0];
    *(uv4*)&As[r][ksg + 8] = *(uv4*)&tmp[8];
  }
  __syncthreads();
  const int wave = tid >> 6, lane = tid & 63;
  const int n = lane & 15, q = lane >> 4;
  const int h = h0b + wave * 16 + n;
  const float* Wg[3] = {Wir, Wiz, Wih};
  const float SCL[3] = {LOG2E, LOG2E, TWOLOG2E};
  bv8 bfrag[3][2];
#pragma unroll
  for (int g = 0; g < 3; ++g)
#pragma unroll
    for (int ks = 0; ks < 2; ++ks) {
      const float* wp = Wg[g] + (size_t)h * Iv + ks * 32 + q * 8;
      float4 w0 = *(const float4*)wp, w1 = *(const float4*)(wp + 4);
      const float s = SCL[g];
      bv8 f;
      f[0] = (short)f2bf(w0.x * s); f[1] = (short)f2bf(w0.y * s);
      f[2] = (short)f2bf(w0.z * s); f[3] = (short)f2bf(w0.w * s);
      f[4] = (short)f2bf(w1.x * s); f[5] = (short)f2bf(w1.y * s);
      f[6] = (short)f2bf(w1.z * s); f[7] = (short)f2bf(w1.w * s);
      bfrag[g][ks] = f;
    }
  const float bs0 = bir[h] * LOG2E, bs1 = biz[h] * LOG2E, bs2 = bih[h] * TWOLOG2E;
#pragma unroll
  for (int sub = 0; sub < 4; ++sub) {
    bv8 a0 = *(const bv8*)&As[sub * 16 + n][q * 8];
    bv8 a1 = *(const bv8*)&As[sub * 16 + n][32 + q * 8];
    fv4 ar = {0.f,0.f,0.f,0.f}, az = {0.f,0.f,0.f,0.f}, ah = {0.f,0.f,0.f,0.f};
    ar = __builtin_amdgcn_mfma_f32_16x16x32_bf16(a0, bfrag[0][0], ar, 0, 0, 0);
    ar = __builtin_amdgcn_mfma_f32_16x16x32_bf16(a1, bfrag[0][1], ar, 0, 0, 0);
    az = __builtin_amdgcn_mfma_f32_16x16x32_bf16(a0, bfrag[1][0], az, 0, 0, 0);
    az = __builtin_amdgcn_mfma_f32_16x16x32_bf16(a1, bfrag[1][1], az, 0, 0, 0);
    ah = __builtin_amdgcn_mfma_f32_16x16x32_bf16(a0, bfrag[2][0], ah, 0, 0, 0);
    ah = __builtin_amdgcn_mfma_f32_16x16x32_bf16(a1, bfrag[2][1], ah, 0, 0, 0);
#pragma unroll
    for (int j = 0; j < 4; ++j) {
      const int row = bt0 + sub * 16 + q * 4 + j;   // C/D: col=lane&15, row=(lane>>4)*4+j
      const size_t slot = (size_t)row * Hv + h;
      irz[slot] = ((unsigned)f2bf(az[j] + bs1) << 16) | (unsigned)f2bf(ar[j] + bs0);
      ihb[slot] = f2bf(ah[j] + bs2);
    }
  }
}

// ---------------------------------------------------------------------------
// K2: the scan. 128 blocks x 1 wave; lane owns h = lane*8..+7 (R2 geometry).
// Matrices pinned in AGPRs ("a" constraint): they are only ever FMA sources
// (VALU reads AGPR directly on CDNA), never DPP/permlane operands, so the
// allocator's VGPR budget holds just state+buffers — no accvgpr shuffling.
// Scales folded: m* carry 1/H and log2e factors; gates use raw exp2.
// ---------------------------------------------------------------------------
struct Buf { uv4 irz0, irz1; usv8 ih; fv4 nz0, nz1; };
#define IRZ(bf, j) ((j) < 4 ? (bf).irz0[(j)] : (bf).irz1[(j) - 4])
#define NZE(bf, j) ((j) < 4 ? (bf).nz0[(j)]  : (bf).nz1[(j) - 4])

__global__ __launch_bounds__(64, 1) void scan_kernel(
    const float* __restrict__ x0, const float* __restrict__ noise,
    const float* __restrict__ Nhr, const float* __restrict__ Mhr,
    const float* __restrict__ Nhz, const float* __restrict__ Mhz,
    const float* __restrict__ Nhh, const float* __restrict__ Mhh,
    unsigned* __restrict__ traj, const unsigned short* __restrict__ ihb,
    float* __restrict__ xlast)
{
  const int b = blockIdx.x, lane = threadIdx.x;
  const int h0 = lane * 8;
  const float scr = (1.0f / 512.0f) * LOG2E;      // into mr, mz
  const float sch = (1.0f / 512.0f) * TWOLOG2E;   // into mh
  fv4 nr[8], nz_[8], nh[8], mr[8], mz[8], mh[8];
#pragma unroll
  for (int j = 0; j < 8; ++j) {
    nr[j]  = *(const fv4*)(Nhr + (size_t)(h0 + j) * 4);
    nz_[j] = *(const fv4*)(Nhz + (size_t)(h0 + j) * 4);
    nh[j]  = *(const fv4*)(Nhh + (size_t)(h0 + j) * 4);
    mr[j]  = *(const fv4*)(Mhr + (size_t)(h0 + j) * 4) * scr;
    mz[j]  = *(const fv4*)(Mhz + (size_t)(h0 + j) * 4) * scr;
    mh[j]  = *(const fv4*)(Mhh + (size_t)(h0 + j) * 4) * sch;
  }
  // Pin the matrices in AGPRs: frees the architectural VGPR budget for
  // state/buffers; FMAs source them directly from AGPR.
#pragma unroll
  for (int j = 0; j < 8; ++j) {
    asm("" : "+a"(nr[j]), "+a"(nz_[j]), "+a"(nh[j]));
    asm("" : "+a"(mr[j]), "+a"(mz[j]), "+a"(mh[j]));
  }
  float x[8];
  {
    fv4 a = *(const fv4*)(x0 + (size_t)b * Hv + h0);
    fv4 c = *(const fv4*)(x0 + (size_t)b * Hv + h0 + 4);
#pragma unroll
    for (int j = 0; j < 4; ++j) { x[j] = a[j]; x[j + 4] = c[j]; }
  }
  const size_t rowbase = (size_t)b * Tv * Hv + h0;
  const size_t nbase = (size_t)b * Hv + h0;
  Buf A, Bb;
  auto LOAD = [&](Buf& bf, int t) {
    const unsigned* p = traj + rowbase + (size_t)t * Hv;
    bf.irz0 = *(const uv4*)p;
    bf.irz1 = *(const uv4*)(p + 4);
    bf.ih = *(const usv8*)(ihb + rowbase + (size_t)t * Hv);
    const float* np = noise + (size_t)t * (Bv * Hv) + nbase;
    bf.nz0 = *(const fv4*)np;
    bf.nz1 = *(const fv4*)(np + 4);
  };
  auto STEP = [&](const Buf& bf, int t) {
    float sr[4] = {0, 0, 0, 0}, sz[4] = {0, 0, 0, 0};
#pragma unroll
    for (int j = 0; j < 8; ++j)
#pragma unroll
      for (int r = 0; r < 4; ++r) {
        sr[r] = fmaf(x[j], nr[j][r], sr[r]);
        sz[r] = fmaf(x[j], nz_[j][r], sz[r]);
      }
#pragma unroll
    for (int r = 0; r < 4; ++r) { sr[r] = wave_red(sr[r]); sz[r] = wave_red(sz[r]); }
    float rx[8], zz[8];
#pragma unroll
    for (int j = 0; j < 8; ++j) {
      // scales already folded into mr/mz and the stored ir/iz
      float hr = fmaf(sr[3], mr[j][3], fmaf(sr[2], mr[j][2], fmaf(sr[1], mr[j][1], sr[0] * mr[j][0])));
      float hz = fmaf(sz[3], mz[j][3], fmaf(sz[2], mz[j][2], fmaf(sz[1], mz[j][1], sz[0] * mz[j][0])));
      unsigned w = IRZ(bf, j);
      float irv = __builtin_bit_cast(float, w << 16);
      float izv = __builtin_bit_cast(float, w & 0xffff0000u);
      float er = __builtin_amdgcn_exp2f(-(irv + hr));
      float ez = __builtin_amdgcn_exp2f(-(izv + hz));
      rx[j] = __builtin_amdgcn_rcpf(1.0f + er) * x[j];
      zz[j] = __builtin_amdgcn_rcpf(1.0f + ez);
    }
    float sh[4] = {0, 0, 0, 0};
#pragma unroll
    for (int j = 0; j < 8; ++j)
#pragma unroll
      for (int r = 0; r < 4; ++r) sh[r] = fmaf(rx[j], nh[j][r], sh[r]);
#pragma unroll
    for (int r = 0; r < 4; ++r) sh[r] = wave_red(sh[r]);
#pragma unroll
    for (int j = 0; j < 8; ++j) {
      float hh = fmaf(sh[3], mh[j][3], fmaf(sh[2], mh[j][2], fmaf(sh[1], mh[j][1], sh[0] * mh[j][0])));
      float a = fmaxf(bf2f(bf.ih[j]) + hh, -44.0f);  // a = 2*log2e*arg; one-sided clamp
      float e = __builtin_amdgcn_exp2f(-a);
      float g = (1.f - e) * __builtin_amdgcn_rcpf(1.f + e);  // tanh(arg)
      x[j] = x[j] + 0.05f * NZE(bf, j) + 0.2f * (1.f - zz[j]) * (g - x[j]);
    }
    float* op = (float*)(traj + rowbase + (size_t)t * Hv);
    fv4 s0 = {x[0], x[1], x[2], x[3]}, s1 = {x[4], x[5], x[6], x[7]};
    *(fv4*)op = s0;
    *(fv4*)(op + 4) = s1;
  };
  LOAD(A, 0);
  for (int t = 0; t < Tv; t += 2) {
    LOAD(Bb, t + 1);
    STEP(A, t);
    if (t + 2 < Tv) LOAD(A, t + 2);
    STEP(Bb, t + 1);
  }
  {
    fv4 s0 = {x[0], x[1], x[2], x[3]}, s1 = {x[4], x[5], x[6], x[7]};
    *(fv4*)(xlast + nbase) = s0;
    *(fv4*)(xlast + nbase + 4) = s1;
  }
}

// ---------------------------------------------------------------------------
// K3: output projection out[bt,o] = traj[bt,:] . W_out[o,:] + b_out[o]
// ---------------------------------------------------------------------------
__global__ __launch_bounds__(256) void outproj_kernel(
    const float* __restrict__ traj, const float* __restrict__ Wout,
    const float* __restrict__ bout, float* __restrict__ out)
{
  __shared__ __align__(16) unsigned short As[64][40];
  const int bt0 = blockIdx.x * 64;
  const int tid = threadIdx.x;
  const int wave = tid >> 6, lane = tid & 63;
  const int n = lane & 15, q = lane >> 4;
  const int o = wave * 16 + n;
  const float bo = bout[o];
  fv4 acc[4] = {{0.f,0.f,0.f,0.f},{0.f,0.f,0.f,0.f},{0.f,0.f,0.f,0.f},{0.f,0.f,0.f,0.f}};
  const int r = tid >> 2, ksg = (tid & 3) * 8;
  for (int ks = 0; ks < 16; ++ks) {
    __syncthreads();
    {
      const float* src = traj + (size_t)(bt0 + r) * Hv + ks * 32 + ksg;
      float4 v0 = *(const float4*)src, v1 = *(const float4*)(src + 4);
      unsigned short tmp[8];
      tmp[0] = f2bf(v0.x); tmp[1] = f2bf(v0.y); tmp[2] = f2bf(v0.z); tmp[3] = f2bf(v0.w);
      tmp[4] = f2bf(v1.x); tmp[5] = f2bf(v1.y); tmp[6] = f2bf(v1.z); tmp[7] = f2bf(v1.w);
      *(uv4*)&As[r][ksg] = *(uv4*)&tmp[0];
    }
    __syncthreads();
    const float* wp = Wout + (size_t)o * Hv + ks * 32 + q * 8;
    float4 w0 = *(const float4*)wp, w1 = *(const float4*)(wp + 4);
    bv8 bf;
    bf[0] = (short)f2bf(w0.x); bf[1] = (short)f2bf(w0.y);
    bf[2] = (short)f2bf(w0.z); bf[3] = (short)f2bf(w0.w);
    bf[4] = (short)f2bf(w1.x); bf[5] = (short)f2bf(w1.y);
    bf[6] = (short)f2bf(w1.z); bf[7] = (short)f2bf(w1.w);
#pragma unroll
    for (int sub = 0; sub < 4; ++sub) {
      bv8 af = *(const bv8*)&As[sub * 16 + n][q * 8];
      acc[sub] = __builtin_amdgcn_mfma_f32_16x16x32_bf16(af, bf, acc[sub], 0, 0, 0);
    }
  }
#pragma unroll
  for (int sub = 0; sub < 4; ++sub)
#pragma unroll
    for (int j = 0; j < 4; ++j) {
      const int row = bt0 + sub * 16 + q * 4 + j;
      out[(size_t)row * Ov + o] = acc[sub][j] + bo;
    }
}

// ---------------------------------------------------------------------------
extern "C" void kernel_launch(void* const* d_in, const int* in_sizes, int n_in,
                              void* d_out, int out_size, void* d_ws, size_t ws_size,
                              hipStream_t stream) {
  const float* u    = (const float*)d_in[0];
  const float* x0   = (const float*)d_in[1];
  const float* noise= (const float*)d_in[2];
  const float* Wir  = (const float*)d_in[3];
  const float* bir  = (const float*)d_in[4];
  const float* Wiz  = (const float*)d_in[5];
  const float* biz  = (const float*)d_in[6];
  const float* Wih  = (const float*)d_in[7];
  const float* bih  = (const float*)d_in[8];
  const float* Nhr  = (const float*)d_in[9];
  const float* Mhr  = (const float*)d_in[10];
  const float* Nhz  = (const float*)d_in[11];
  const float* Mhz  = (const float*)d_in[12];
  const float* Nhh  = (const float*)d_in[13];
  const float* Mhh  = (const float*)d_in[14];
  const float* Wout = (const float*)d_in[15];
  const float* bout = (const float*)d_in[16];

  float* out   = (float*)d_out;                    // [B,T,O]
  float* xlast = out + (size_t)Bv * Tv * Ov;       // [B,H]
  float* traj  = xlast + (size_t)Bv * Hv;          // [B,T,H]
  unsigned short* ihbuf = (unsigned short*)d_ws;   // [B*T*H] bf16 (64 MiB)

  proj_kernel<<<dim3(1024, 8, 1), 256, 0, stream>>>(
      u, Wir, bir, Wiz, biz, Wih, bih, (unsigned*)traj, ihbuf);
  scan_kernel<<<dim3(128, 1, 1), 64, 0, stream>>>(
      x0, noise, Nhr, Mhr, Nhz, Mhz, Nhh, Mhh, (unsigned*)traj, ihbuf, xlast);
  outproj_kernel<<<dim3(1024, 1, 1), 256, 0, stream>>>(traj, Wout, bout, out);
}

// Round 7
// 691.707 us; speedup vs baseline: 2.3516x; 1.0476x over previous
//
#include <hip/hip_runtime.h>
#include <hip/hip_bf16.h>
#include <stdint.h>

#define Bv 128
#define Tv 512
#define Iv 64
#define Hv 512
#define Ov 64

typedef __attribute__((ext_vector_type(8))) short bv8;    // 8 bf16 for MFMA A/B
typedef __attribute__((ext_vector_type(4))) float fv4;    // MFMA C/D
typedef __attribute__((ext_vector_type(4))) unsigned uv4;
typedef __attribute__((ext_vector_type(2))) unsigned uv2;
typedef __attribute__((ext_vector_type(8))) unsigned short usv8;

#define LOG2E 1.44269504f
#define TWOLOG2E 2.88539008f

static __device__ __forceinline__ unsigned short f2bf(float f) {
  unsigned u = __builtin_bit_cast(unsigned, f);
  u += 0x7fffu + ((u >> 16) & 1u);           // RNE
  return (unsigned short)(u >> 16);
}
static __device__ __forceinline__ float bf2f(unsigned short s) {
  return __builtin_bit_cast(float, ((unsigned)s) << 16);
}

// DPP add: v += v_from_lane_pattern (patterns within 16-lane rows)
template <int CTRL>
static __device__ __forceinline__ float dpp_add(float v) {
  int t = __builtin_amdgcn_update_dpp(0, __builtin_bit_cast(int, v), CTRL, 0xF, 0xF, true);
  return v + __builtin_bit_cast(float, t);
}

// Full 64-lane sum, result replicated in every lane. VALU-latency only.
static __device__ __forceinline__ float wave_red(float v) {
  v = dpp_add<0xB1>(v);   // + v[lane^1]
  v = dpp_add<0x4E>(v);   // + v[lane^2]
  v = dpp_add<0x124>(v);  // row_ror:4
  v = dpp_add<0x128>(v);  // row_ror:8
  unsigned a = __builtin_bit_cast(unsigned, v);
  uv2 p = __builtin_amdgcn_permlane16_swap(a, a, false, false);
  v = __builtin_bit_cast(float, p[0]) + __builtin_bit_cast(float, p[1]);  // + v[lane^16]
  a = __builtin_bit_cast(unsigned, v);
  uv2 q = __builtin_amdgcn_permlane32_swap(a, a, false, false);
  v = __builtin_bit_cast(float, q[0]) + __builtin_bit_cast(float, q[1]);  // + v[lane^32]
  return v;
}

// ---------------------------------------------------------------------------
// K1: input projections. ir|iz packed bf16x2 -> traj region (u32/slot),
//     ih bf16 -> ws.  C = u[bt,64] @ W^T[64,512] via mfma_f32_16x16x32_bf16.
// log2e folded into W_ir/b_ir and W_iz/b_iz; 2*log2e into W_ih/b_ih, so the
// scan kernel can use raw v_exp_f32 (exp2) with no argument scaling.
// ---------------------------------------------------------------------------
__global__ __launch_bounds__(256) void proj_kernel(
    const float* __restrict__ u,
    const float* __restrict__ Wir, const float* __restrict__ bir,
    const float* __restrict__ Wiz, const float* __restrict__ biz,
    const float* __restrict__ Wih, const float* __restrict__ bih,
    unsigned* __restrict__ irz, unsigned short* __restrict__ ihb)
{
  __shared__ __align__(16) unsigned short As[64][72];  // bf16, padded stride
  const int bt0 = blockIdx.x * 64;
  const int h0b = blockIdx.y * 64;
  const int tid = threadIdx.x;
  {  // stage u tile f32 -> bf16 LDS
    const int r = tid >> 2, ksg = (tid & 3) * 16;
    const float* src = u + (size_t)(bt0 + r) * Iv + ksg;
    unsigned short tmp[16];
#pragma unroll
    for (int i = 0; i < 16; i += 4) {
      float4 v = *(const float4*)(src + i);
      tmp[i] = f2bf(v.x); tmp[i+1] = f2bf(v.y); tmp[i+2] = f2bf(v.z); tmp[i+3] = f2bf(v.w);
    }
    *(uv4*)&As[r][ksg]     = *(uv4*)&tmp[0];
    *(uv4*)&As[r][ksg + 8] = *(uv4*)&tmp[8];
  }
  __syncthreads();
  const int wave = tid >> 6, lane = tid & 63;
  const int n = lane & 15, q = lane >> 4;
  const int h = h0b + wave * 16 + n;
  const float* Wg[3] = {Wir, Wiz, Wih};
  const float SCL[3] = {LOG2E, LOG2E, TWOLOG2E};
  bv8 bfrag[3][2];
#pragma unroll
  for (int g = 0; g < 3; ++g)
#pragma unroll
    for (int ks = 0; ks < 2; ++ks) {
      const float* wp = Wg[g] + (size_t)h * Iv + ks * 32 + q * 8;
      float4 w0 = *(const float4*)wp, w1 = *(const float4*)(wp + 4);
      const float s = SCL[g];
      bv8 f;
      f[0] = (short)f2bf(w0.x * s); f[1] = (short)f2bf(w0.y * s);
      f[2] = (short)f2bf(w0.z * s); f[3] = (short)f2bf(w0.w * s);
      f[4] = (short)f2bf(w1.x * s); f[5] = (short)f2bf(w1.y * s);
      f[6] = (short)f2bf(w1.z * s); f[7] = (short)f2bf(w1.w * s);
      bfrag[g][ks] = f;
    }
  const float bs0 = bir[h] * LOG2E, bs1 = biz[h] * LOG2E, bs2 = bih[h] * TWOLOG2E;
#pragma unroll
  for (int sub = 0; sub < 4; ++sub) {
    bv8 a0 = *(const bv8*)&As[sub * 16 + n][q * 8];
    bv8 a1 = *(const bv8*)&As[sub * 16 + n][32 + q * 8];
    fv4 ar = {0.f,0.f,0.f,0.f}, az = {0.f,0.f,0.f,0.f}, ah = {0.f,0.f,0.f,0.f};
    ar = __builtin_amdgcn_mfma_f32_16x16x32_bf16(a0, bfrag[0][0], ar, 0, 0, 0);
    ar = __builtin_amdgcn_mfma_f32_16x16x32_bf16(a1, bfrag[0][1], ar, 0, 0, 0);
    az = __builtin_amdgcn_mfma_f32_16x16x32_bf16(a0, bfrag[1][0], az, 0, 0, 0);
    az = __builtin_amdgcn_mfma_f32_16x16x32_bf16(a1, bfrag[1][1], az, 0, 0, 0);
    ah = __builtin_amdgcn_mfma_f32_16x16x32_bf16(a0, bfrag[2][0], ah, 0, 0, 0);
    ah = __builtin_amdgcn_mfma_f32_16x16x32_bf16(a1, bfrag[2][1], ah, 0, 0, 0);
#pragma unroll
    for (int j = 0; j < 4; ++j) {
      const int row = bt0 + sub * 16 + q * 4 + j;   // C/D: col=lane&15, row=(lane>>4)*4+j
      const size_t slot = (size_t)row * Hv + h;
      irz[slot] = ((unsigned)f2bf(az[j] + bs1) << 16) | (unsigned)f2bf(ar[j] + bs0);
      ihb[slot] = f2bf(ah[j] + bs2);
    }
  }
}

// ---------------------------------------------------------------------------
// K2: the scan. 128 blocks x 1 wave; lane owns h = lane*8..+7 (R2 geometry).
// Matrices live in LDS (48 KB), NOT registers: the live register set drops
// to ~110 (state + double-buffers + temps) so allocation is purely
// architectural — no acc/arch shuffle fat. Reads are ds_read_b128 with an
// XOR slot swizzle (slot = j ^ (lane&7)) so each 8-lane group tiles the
// full 128B bank row per beat -> conflict-free.
// Scales folded into the LDS copies of M (1/H * log2e factors); gates use
// raw exp2 against the pre-scaled ir/iz/ih from K1.
// ---------------------------------------------------------------------------
struct Buf { uv4 irz0, irz1; usv8 ih; fv4 nz0, nz1; };
#define IRZ(bf, j) ((j) < 4 ? (bf).irz0[(j)] : (bf).irz1[(j) - 4])
#define NZE(bf, j) ((j) < 4 ? (bf).nz0[(j)]  : (bf).nz1[(j) - 4])

__global__ __launch_bounds__(64, 1) void scan_kernel(
    const float* __restrict__ x0, const float* __restrict__ noise,
    const float* __restrict__ Nhr, const float* __restrict__ Mhr,
    const float* __restrict__ Nhz, const float* __restrict__ Mhz,
    const float* __restrict__ Nhh, const float* __restrict__ Mhh,
    unsigned* __restrict__ traj, const unsigned short* __restrict__ ihb,
    float* __restrict__ xlast)
{
  __shared__ __align__(16) float Wlds[6 * 2048];   // 48 KB: nr,nz,nh,mr,mz,mh
  const int b = blockIdx.x, lane = threadIdx.x;
  const int h0 = lane * 8;
  const int lbase = lane * 32;          // 32 floats = 128B per lane
  const int xr4 = (lane & 7) * 4;       // XOR swizzle, float units

  // one-time init: each lane writes its own 8 rows per matrix, swizzled.
  {
    const float scr = (1.0f / 512.0f) * LOG2E;      // into mr, mz
    const float sch = (1.0f / 512.0f) * TWOLOG2E;   // into mh
    const float* gsrc[6] = {Nhr, Nhz, Nhh, Mhr, Mhz, Mhh};
    const float scl[6] = {1.f, 1.f, 1.f, scr, scr, sch};
#pragma unroll
    for (int m = 0; m < 6; ++m)
#pragma unroll
      for (int j = 0; j < 8; ++j) {
        fv4 v = *(const fv4*)(gsrc[m] + (size_t)(h0 + j) * 4) * scl[m];
        *(fv4*)&Wlds[m * 2048 + lbase + ((j * 4) ^ xr4)] = v;
      }
  }
  // single wave: ds_write->ds_read ordering handled by lgkmcnt the compiler
  // inserts; no barrier needed.

#define MAT(m, j) (*(const fv4*)&Wlds[(m) * 2048 + lbase + (((j) * 4) ^ xr4)])

  float x[8];
  {
    fv4 a = *(const fv4*)(x0 + (size_t)b * Hv + h0);
    fv4 c = *(const fv4*)(x0 + (size_t)b * Hv + h0 + 4);
#pragma unroll
    for (int j = 0; j < 4; ++j) { x[j] = a[j]; x[j + 4] = c[j]; }
  }
  const size_t rowbase = (size_t)b * Tv * Hv + h0;
  const size_t nbase = (size_t)b * Hv + h0;
  Buf A, Bb;
  auto LOAD = [&](Buf& bf, int t) {
    const unsigned* p = traj + rowbase + (size_t)t * Hv;
    bf.irz0 = *(const uv4*)p;
    bf.irz1 = *(const uv4*)(p + 4);
    bf.ih = *(const usv8*)(ihb + rowbase + (size_t)t * Hv);
    const float* np = noise + (size_t)t * (Bv * Hv) + nbase;
    bf.nz0 = *(const fv4*)np;
    bf.nz1 = *(const fv4*)(np + 4);
  };
  auto STEP = [&](const Buf& bf, int t) {
    float sr[4] = {0, 0, 0, 0}, sz[4] = {0, 0, 0, 0};
#pragma unroll
    for (int j = 0; j < 8; ++j) {
      fv4 nrj = MAT(0, j), nzj = MAT(1, j);
#pragma unroll
      for (int r = 0; r < 4; ++r) {
        sr[r] = fmaf(x[j], nrj[r], sr[r]);
        sz[r] = fmaf(x[j], nzj[r], sz[r]);
      }
    }
#pragma unroll
    for (int r = 0; r < 4; ++r) { sr[r] = wave_red(sr[r]); sz[r] = wave_red(sz[r]); }
    float rx[8], zz[8];
#pragma unroll
    for (int j = 0; j < 8; ++j) {
      fv4 mrj = MAT(3, j), mzj = MAT(4, j);
      float hr = fmaf(sr[3], mrj[3], fmaf(sr[2], mrj[2], fmaf(sr[1], mrj[1], sr[0] * mrj[0])));
      float hz = fmaf(sz[3], mzj[3], fmaf(sz[2], mzj[2], fmaf(sz[1], mzj[1], sz[0] * mzj[0])));
      unsigned w = IRZ(bf, j);
      float irv = __builtin_bit_cast(float, w << 16);
      float izv = __builtin_bit_cast(float, w & 0xffff0000u);
      float er = __builtin_amdgcn_exp2f(-(irv + hr));
      float ez = __builtin_amdgcn_exp2f(-(izv + hz));
      rx[j] = __builtin_amdgcn_rcpf(1.0f + er) * x[j];
      zz[j] = __builtin_amdgcn_rcpf(1.0f + ez);
    }
    float sh[4] = {0, 0, 0, 0};
#pragma unroll
    for (int j = 0; j < 8; ++j) {
      fv4 nhj = MAT(2, j);
#pragma unroll
      for (int r = 0; r < 4; ++r) sh[r] = fmaf(rx[j], nhj[r], sh[r]);
    }
#pragma unroll
    for (int r = 0; r < 4; ++r) sh[r] = wave_red(sh[r]);
#pragma unroll
    for (int j = 0; j < 8; ++j) {
      fv4 mhj = MAT(5, j);
      float hh = fmaf(sh[3], mhj[3], fmaf(sh[2], mhj[2], fmaf(sh[1], mhj[1], sh[0] * mhj[0])));
      float a = fmaxf(bf2f(bf.ih[j]) + hh, -44.0f);  // a = 2*log2e*arg; one-sided clamp
      float e = __builtin_amdgcn_exp2f(-a);
      float g = (1.f - e) * __builtin_amdgcn_rcpf(1.f + e);  // tanh(arg)
      x[j] = x[j] + 0.05f * NZE(bf, j) + 0.2f * (1.f - zz[j]) * (g - x[j]);
    }
    float* op = (float*)(traj + rowbase + (size_t)t * Hv);
    fv4 s0 = {x[0], x[1], x[2], x[3]}, s1 = {x[4], x[5], x[6], x[7]};
    *(fv4*)op = s0;
    *(fv4*)(op + 4) = s1;
  };
  LOAD(A, 0);
  for (int t = 0; t < Tv; t += 2) {
    LOAD(Bb, t + 1);
    STEP(A, t);
    if (t + 2 < Tv) LOAD(A, t + 2);
    STEP(Bb, t + 1);
  }
  {
    fv4 s0 = {x[0], x[1], x[2], x[3]}, s1 = {x[4], x[5], x[6], x[7]};
    *(fv4*)(xlast + nbase) = s0;
    *(fv4*)(xlast + nbase + 4) = s1;
  }
#undef MAT
}

// ---------------------------------------------------------------------------
// K3: output projection out[bt,o] = traj[bt,:] . W_out[o,:] + b_out[o]
// ---------------------------------------------------------------------------
__global__ __launch_bounds__(256) void outproj_kernel(
    const float* __restrict__ traj, const float* __restrict__ Wout,
    const float* __restrict__ bout, float* __restrict__ out)
{
  __shared__ __align__(16) unsigned short As[64][40];
  const int bt0 = blockIdx.x * 64;
  const int tid = threadIdx.x;
  const int wave = tid >> 6, lane = tid & 63;
  const int n = lane & 15, q = lane >> 4;
  const int o = wave * 16 + n;
  const float bo = bout[o];
  fv4 acc[4] = {{0.f,0.f,0.f,0.f},{0.f,0.f,0.f,0.f},{0.f,0.f,0.f,0.f},{0.f,0.f,0.f,0.f}};
  const int r = tid >> 2, ksg = (tid & 3) * 8;
  for (int ks = 0; ks < 16; ++ks) {
    __syncthreads();
    {
      const float* src = traj + (size_t)(bt0 + r) * Hv + ks * 32 + ksg;
      float4 v0 = *(const float4*)src, v1 = *(const float4*)(src + 4);
      unsigned short tmp[8];
      tmp[0] = f2bf(v0.x); tmp[1] = f2bf(v0.y); tmp[2] = f2bf(v0.z); tmp[3] = f2bf(v0.w);
      tmp[4] = f2bf(v1.x); tmp[5] = f2bf(v1.y); tmp[6] = f2bf(v1.z); tmp[7] = f2bf(v1.w);
      *(uv4*)&As[r][ksg] = *(uv4*)&tmp[0];
    }
    __syncthreads();
    const float* wp = Wout + (size_t)o * Hv + ks * 32 + q * 8;
    float4 w0 = *(const float4*)wp, w1 = *(const float4*)(wp + 4);
    bv8 bf;
    bf[0] = (short)f2bf(w0.x); bf[1] = (short)f2bf(w0.y);
    bf[2] = (short)f2bf(w0.z); bf[3] = (short)f2bf(w0.w);
    bf[4] = (short)f2bf(w1.x); bf[5] = (short)f2bf(w1.y);
    bf[6] = (short)f2bf(w1.z); bf[7] = (short)f2bf(w1.w);
#pragma unroll
    for (int sub = 0; sub < 4; ++sub) {
      bv8 af = *(const bv8*)&As[sub * 16 + n][q * 8];
      acc[sub] = __builtin_amdgcn_mfma_f32_16x16x32_bf16(af, bf, acc[sub], 0, 0, 0);
    }
  }
#pragma unroll
  for (int sub = 0; sub < 4; ++sub)
#pragma unroll
    for (int j = 0; j < 4; ++j) {
      const int row = bt0 + sub * 16 + q * 4 + j;
      out[(size_t)row * Ov + o] = acc[sub][j] + bo;
    }
}

// ---------------------------------------------------------------------------
extern "C" void kernel_launch(void* const* d_in, const int* in_sizes, int n_in,
                              void* d_out, int out_size, void* d_ws, size_t ws_size,
                              hipStream_t stream) {
  const float* u    = (const float*)d_in[0];
  const float* x0   = (const float*)d_in[1];
  const float* noise= (const float*)d_in[2];
  const float* Wir  = (const float*)d_in[3];
  const float* bir  = (const float*)d_in[4];
  const float* Wiz  = (const float*)d_in[5];
  const float* biz  = (const float*)d_in[6];
  const float* Wih  = (const float*)d_in[7];
  const float* bih  = (const float*)d_in[8];
  const float* Nhr  = (const float*)d_in[9];
  const float* Mhr  = (const float*)d_in[10];
  const float* Nhz  = (const float*)d_in[11];
  const float* Mhz  = (const float*)d_in[12];
  const float* Nhh  = (const float*)d_in[13];
  const float* Mhh  = (const float*)d_in[14];
  const float* Wout = (const float*)d_in[15];
  const float* bout = (const float*)d_in[16];

  float* out   = (float*)d_out;                    // [B,T,O]
  float* xlast = out + (size_t)Bv * Tv * Ov;       // [B,H]
  float* traj  = xlast + (size_t)Bv * Hv;          // [B,T,H]
  unsigned short* ihbuf = (unsigned short*)d_ws;   // [B*T*H] bf16 (64 MiB)

  proj_kernel<<<dim3(1024, 8, 1), 256, 0, stream>>>(
      u, Wir, bir, Wiz, biz, Wih, bih, (unsigned*)traj, ihbuf);
  scan_kernel<<<dim3(128, 1, 1), 64, 0, stream>>>(
      x0, noise, Nhr, Mhr, Nhz, Mhz, Nhh, Mhh, (unsigned*)traj, ihbuf, xlast);
  outproj_kernel<<<dim3(1024, 1, 1), 256, 0, stream>>>(traj, Wout, bout, out);
}